// Round 11
// baseline (56.301 us; speedup 1.0000x reference)
//
#include <hip/hip_runtime.h>

namespace {

constexpr int kB = 256;
constexpr int kT = 1024;
constexpr int kC = 64;
constexpr int kS = 20;       // segments per chain
constexpr int kL = 8;        // burn-in steps (Birkhoff contraction ~0.2/step)
constexpr int kNT = kT - 1;  // 1023 transitions
constexpr int kWavesPerBlk = 4;

typedef _Float16 half1_t;
typedef _Float16 half2_t __attribute__((ext_vector_type(2)));

#if __has_builtin(__builtin_amdgcn_fdot2)
#define HAVE_FDOT2 1
#else
#define HAVE_FDOT2 0
#endif

__device__ __forceinline__ float dot2f(half2_t a, half2_t b, float c) {
#if HAVE_FDOT2
  return __builtin_amdgcn_fdot2(a, b, c, false);
#else
  return c + (float)a.x * (float)b.x + (float)a.y * (float)b.y;
#endif
}

__device__ __forceinline__ half2_t as_h2(unsigned int u) {
  return __builtin_bit_cast(half2_t, u);
}

__device__ __forceinline__ float wave_sum(float v) {
#pragma unroll
  for (int off = 32; off >= 1; off >>= 1) v += __shfl_xor(v, off, 64);
  return v;
}

// workspace float layout:
//   [0    .. kS*256)   val[ss][b] : per-segment partial log2 sums
//   [8192 .. 8448)     pe[b]      : gold-path energy

// 1280 blocks x 256 threads; each of the 4 waves in a block runs one
// independent (segment, batch) chain (own pbuf slice, no barriers).
// lane = class. Linear-domain forward recursion, f16 state in LDS, f16 W in
// regs, immediate lane-0 pow2 renorm via readfirstlane (SALU; no shuffles in
// the hot loop). Segments ss>0 start uniform + kL burn-in steps (Birkhoff
// contraction ~0.2/step); partial log2 growth sums telescope exactly.
__global__ __launch_bounds__(256) void crf_seg(
    const float* __restrict__ x,    // [B,T,C]
    const float* __restrict__ U,    // [C,C]
    const float* __restrict__ bs,   // [C]
    const float* __restrict__ be,   // [C]
    const int*   __restrict__ y,    // [B,T]
    float*       __restrict__ wsf)
{
  const int wid   = threadIdx.x >> 6;
  const int j     = threadIdx.x & 63;
  const int chain = blockIdx.x * kWavesPerBlk + wid;   // = ss*256 + b
  const int ss    = chain >> 8;
  const int b     = chain & 255;

  __shared__ __align__(16) half1_t pbuf[kWavesPerBlk][kC];

  const float* xbase = x + (size_t)b * kT * kC;
  const float* xcol  = xbase + j;

  // ---- gold-path energy prepass (segment-0 chains only; t-parallel) ----
  if (ss == 0) {
    const int* yrow = y + (size_t)b * kT;
    float pe = 0.f;
    const int t0 = j * 16;
    int yv[17];
#pragma unroll
    for (int k = 0; k < 16; ++k) yv[k + 1] = yrow[t0 + k];
    yv[0] = (j > 0) ? yrow[t0 - 1] : 0;
#pragma unroll
    for (int k = 0; k < 16; ++k) {
      const int t = t0 + k;
      pe += xbase[(size_t)t * kC + yv[k + 1]];          // emission
      if (t >= 1) pe += U[yv[k] * kC + yv[k + 1]];      // transition
    }
    if (j == 0)  pe += bs[yv[1]];    // boundary on y[0]
    if (j == 63) pe += be[yv[16]];   // boundary on y[T-1]
    pe = wave_sum(pe);
    if (j == 0) wsf[8192 + b] = pe;
  }

  // ---- W column for this lane, f16 pairs: Wp[w] = (W[2w][j], W[2w+1][j]) ----
  half2_t Wp[32];
#pragma unroll
  for (int w = 0; w < 32; ++w) {
    half2_t hw;
    hw.x = (half1_t)__expf(U[(2 * w + 0) * kC + j]);
    hw.y = (half1_t)__expf(U[(2 * w + 1) * kC + j]);
    Wp[w] = hw;
  }
  const float bej = be[j];

  // transition range this segment is accountable for: [t_lo, t_hi]
  const int t_lo    = (kNT * ss) / kS + 1;
  const int t_hi    = (kNT * (ss + 1)) / kS;
  const int t_first = (ss == 0) ? 1 : (t_lo - kL);   // incl. burn-in
  const int nburn   = (ss == 0) ? 0 : kL;
  const int ntot    = t_hi - t_first + 1;

  int   sacc = 0;
  float pl;
  if (ss == 0) {
    // exact alpha_0 = exp(x_0 + b_start), renormalized
    const float pn = __expf(xcol[0] + bs[j]);
    const int eb = (__builtin_amdgcn_readfirstlane(__float_as_uint(pn)) >> 23) & 255;
    sacc = eb - 127;
    pl = pn * __uint_as_float((unsigned)(254 - eb) << 23);
    pbuf[wid][j] = (half1_t)pl;
  } else {
    pl = 1.f;                      // uniform start (direction converges)
    pbuf[wid][j] = (half1_t)1.f;
  }
  float ref = 0.f;                 // log2 reference at accountability start

  // preload group 0
  float xb[8];
#pragma unroll
  for (int k = 0; k < 8; ++k) {
    int t = t_first + k; t = (t > kNT) ? kNT : t;
    xb[k] = xcol[t * kC];
  }

  for (int base = 0; base < ntot; base += 8) {
    float xn[8];
    const bool more = (base + 8 < ntot);
    if (more) {
#pragma unroll
      for (int k = 0; k < 8; ++k) {
        int t = t_first + base + 8 + k; t = (t > kNT) ? kNT : t;
        xn[k] = xcol[t * kC];
      }
    }

    // E for this group — off the p critical path
    float Eb[8];
#pragma unroll
    for (int k = 0; k < 8; ++k) {
      float xe = xb[k];
      if (t_first + base + k == kNT) xe += bej;   // t == T-1 boundary
      Eb[k] = __expf(xe);
    }

#pragma unroll
    for (int k = 0; k < 8; ++k) {
      if (base + k < ntot) {
        // one recursion step: p <- (p W) * E, f16 LDS broadcast
        const uint4* sh = reinterpret_cast<const uint4*>(pbuf[wid]);
        float acc[8];
#pragma unroll
        for (int q = 0; q < 8; ++q) {
          const uint4 vv = sh[q];
          float a;
          a = dot2f(as_h2(vv.x), Wp[4 * q + 0], 0.f);
          a = dot2f(as_h2(vv.y), Wp[4 * q + 1], a);
          a = dot2f(as_h2(vv.z), Wp[4 * q + 2], a);
          a = dot2f(as_h2(vv.w), Wp[4 * q + 3], a);
          acc[q] = a;
        }
        const float s01 = acc[0] + acc[1], s23 = acc[2] + acc[3];
        const float s45 = acc[4] + acc[5], s67 = acc[6] + acc[7];
        const float pn = ((s01 + s23) + (s45 + s67)) * Eb[k];

        // immediate lane-0 pow2 renorm (SALU broadcast)
        const int eb = (__builtin_amdgcn_readfirstlane(__float_as_uint(pn)) >> 23) & 255;
        sacc += eb - 127;
        pl = pn * __uint_as_float((unsigned)(254 - eb) << 23);
        pbuf[wid][j] = (half1_t)pl;

        // end of burn-in: snapshot log2 |p|_1 (butterfly; off hot path)
        if (base + k + 1 == nburn) {
          const float ps = wave_sum(pl);
          ref = __log2f(ps) + (float)sacc;
        }
      }
    }

    if (more) {
#pragma unroll
      for (int k = 0; k < 8; ++k) xb[k] = xn[k];
    }
  }

  // ---- partial: log2 |alpha_{t_hi}| - log2 |alpha_{t_lo-1}| ----
  const float ps  = wave_sum(pl);
  const float val = (__log2f(ps) + (float)sacc) - ref;
  if (j == 0) wsf[ss * 256 + b] = val;
}

// out[b] = ln2 * sum_ss val[ss][b] - pe[b]
__global__ __launch_bounds__(64, 1) void crf_combine(
    const float* __restrict__ wsf, float* __restrict__ out)
{
  const int b = blockIdx.x;
  const int j = threadIdx.x & 63;

  float v = (j < kS) ? wsf[j * 256 + b] : 0.f;
  v = wave_sum(v);

  if (j == 0) {
    out[b] = 0.69314718055994531f * v - wsf[8192 + b];
  }
}

}  // namespace

extern "C" void kernel_launch(void* const* d_in, const int* in_sizes, int n_in,
                              void* d_out, int out_size, void* d_ws, size_t ws_size,
                              hipStream_t stream) {
  const float* x  = (const float*)d_in[0];
  const float* U  = (const float*)d_in[1];
  const float* bs = (const float*)d_in[2];
  const float* be = (const float*)d_in[3];
  const int*   y  = (const int*)d_in[4];
  float* out = (float*)d_out;
  float* wsf = (float*)d_ws;

  crf_seg<<<(kS * kB) / kWavesPerBlk, 256, 0, stream>>>(x, U, bs, be, y, wsf);
  crf_combine<<<kB, 64, 0, stream>>>(wsf, out);
}

// Round 12
// 33.638 us; speedup vs baseline: 1.6737x; 1.6737x over previous
//
#include <hip/hip_runtime.h>

namespace {

constexpr int kB = 256;
constexpr int kT = 1024;
constexpr int kC = 64;
constexpr int kS = 64;       // segments per chain
constexpr int kL = 8;        // burn-in steps (Birkhoff contraction ~0.2/step)
constexpr int kNT = kT - 1;  // transitions 1..1023

typedef _Float16 half1_t;
typedef _Float16 half4_t __attribute__((ext_vector_type(4)));
typedef float    f32x4  __attribute__((ext_vector_type(4)));

__device__ __forceinline__ float wave_sum(float v) {
#pragma unroll
  for (int off = 32; off >= 1; off >>= 1) v += __shfl_xor(v, off, 64);
  return v;
}

// reduce across the 4 lanes {l, l^16, l^32, l^48} that hold one chain
__device__ __forceinline__ float chain_max(float v) {
  v = fmaxf(v, __shfl_xor(v, 16, 64));
  v = fmaxf(v, __shfl_xor(v, 32, 64));
  return v;
}
__device__ __forceinline__ float chain_sum(float v) {
  v += __shfl_xor(v, 16, 64);
  v += __shfl_xor(v, 32, 64);
  return v;
}

// ws layout (floats): [0, 16384) val[ss][b]; [16384, 16640) pe[b]

// Blocks [0,256): 4 waves each, wave = (ss, batch-group-of-16). 16 chains per
// wave, state P = 64 classes x 16 chains held as four 16x16 MFMA B-fragments.
// Step: D[mb] = sum_kb mfma(Wt[mb][kb], P[kb]); P_new = cvt_f16(D*E*2^-e).
// D-fragment layout == B-fragment layout -> zero data movement between steps,
// no LDS anywhere in the loop. Delay-1 dead-beat pow2 renorm per chain
// (e measured via reg-max tree + 2 shfl_xor, off the serial path).
// Blocks [256,320): path-energy prepass, wave = one batch.
__global__ __launch_bounds__(256) void crf_seg(
    const float* __restrict__ x,    // [B,T,C]
    const float* __restrict__ U,    // [C,C]
    const float* __restrict__ bs,   // [C]
    const float* __restrict__ be,   // [C]
    const int*   __restrict__ y,    // [B,T]
    float*       __restrict__ wsf)
{
  const int bid = blockIdx.x;
  const int wid = threadIdx.x >> 6;
  const int j   = threadIdx.x & 63;

  if (bid >= 256) {
    // ---- gold-path energy: wave = one batch, t-parallel 16/lane ----
    const int b = (bid - 256) * 4 + wid;
    const float* xbase = x + (size_t)b * kT * kC;
    const int*   yrow  = y + (size_t)b * kT;
    float pe = 0.f;
    const int t0 = j * 16;
    int yv[17];
#pragma unroll
    for (int k = 0; k < 16; ++k) yv[k + 1] = yrow[t0 + k];
    yv[0] = (j > 0) ? yrow[t0 - 1] : 0;
#pragma unroll
    for (int k = 0; k < 16; ++k) {
      const int t = t0 + k;
      pe += xbase[(size_t)t * kC + yv[k + 1]];
      if (t >= 1) pe += U[yv[k] * kC + yv[k + 1]];
    }
    if (j == 0)  pe += bs[yv[1]];
    if (j == 63) pe += be[yv[16]];
    pe = wave_sum(pe);
    if (j == 0) wsf[kS * kB + b] = pe;
    return;
  }

  const int id = bid * 4 + wid;   // 0..1023
  const int ss = id >> 4;         // segment
  const int bg = id & 15;         // batch group
  const int q  = j >> 4;          // k/m quad selector
  const int r  = j & 15;          // chain column n (and A-row m)
  const int bn = bg * 16 + r;     // this lane's batch

  // ---- Wt A-fragments: A[m=r][k=4q+i] of tile (mb,kb) = exp(U[16kb+k][16mb+m])
  half4_t W[4][4];
#pragma unroll
  for (int mb = 0; mb < 4; ++mb)
#pragma unroll
    for (int kb = 0; kb < 4; ++kb) {
      half4_t w;
#pragma unroll
      for (int i = 0; i < 4; ++i)
        w[i] = (half1_t)__expf(U[(16 * kb + 4 * q + i) * kC + 16 * mb + r]);
      W[mb][kb] = w;
    }

  f32x4 be4[4];
#pragma unroll
  for (int mb = 0; mb < 4; ++mb)
    be4[mb] = *reinterpret_cast<const f32x4*>(be + 16 * mb + 4 * q);

  const int t_lo    = (kNT * ss) / kS + 1;
  const int t_hi    = (kNT * (ss + 1)) / kS;
  const int t_first = (ss == 0) ? 1 : (t_lo - kL);
  const int nburn   = (ss == 0) ? 0 : kL;
  const int nsteps  = t_hi - t_first + 1;   // <= 24

  const float* xlane = x + (size_t)bn * kT * kC + 4 * q;

  half4_t P[4];
  int   sacc  = 0;   // applied pow2 exponents (per chain, lane-consistent)
  int   eprev = 0;   // delay-1 exponent
  float ref   = 0.f;

  if (ss == 0) {
    // exact alpha_0 = exp(x_0 + b_start), immediate per-chain renorm
    float pv[4][4];
    float m = 0.f;
#pragma unroll
    for (int kb = 0; kb < 4; ++kb) {
      const f32x4 xv = *reinterpret_cast<const f32x4*>(xlane + 16 * kb);
      const f32x4 bv = *reinterpret_cast<const f32x4*>(bs + 16 * kb + 4 * q);
#pragma unroll
      for (int i = 0; i < 4; ++i) {
        pv[kb][i] = __expf(xv[i] + bv[i]);
        m = fmaxf(m, pv[kb][i]);
      }
    }
    m = chain_max(m);
    const int e = ((__float_as_uint(m) >> 23) & 255) - 127;
    sacc = e;
    const float sc = __uint_as_float((unsigned)(127 - e) << 23);
#pragma unroll
    for (int kb = 0; kb < 4; ++kb) {
      half4_t p;
#pragma unroll
      for (int i = 0; i < 4; ++i) p[i] = (half1_t)(pv[kb][i] * sc);
      P[kb] = p;
    }
  } else {
#pragma unroll
    for (int kb = 0; kb < 4; ++kb) {
      half4_t p;
#pragma unroll
      for (int i = 0; i < 4; ++i) p[i] = (half1_t)1.0f;
      P[kb] = p;
    }
  }

  // depth-2 x prefetch
  f32x4 xa[4], xb_[4];
#pragma unroll
  for (int mb = 0; mb < 4; ++mb)
    xa[mb] = *reinterpret_cast<const f32x4*>(xlane + (size_t)t_first * kC + 16 * mb);
#pragma unroll
  for (int mb = 0; mb < 4; ++mb)
    xb_[mb] = *reinterpret_cast<const f32x4*>(xlane + (size_t)(t_first + 1) * kC + 16 * mb);

  float Sfin = 0.f;

  for (int s = 0; s < nsteps; ++s) {
    const int t = t_first + s;

    f32x4 xc[4];
    if (s + 2 < nsteps) {
#pragma unroll
      for (int mb = 0; mb < 4; ++mb)
        xc[mb] = *reinterpret_cast<const f32x4*>(xlane + (size_t)(t + 2) * kC + 16 * mb);
    } else {
#pragma unroll
      for (int mb = 0; mb < 4; ++mb) xc[mb] = f32x4{0.f, 0.f, 0.f, 0.f};
    }

    // E for this step (independent of MFMA chain; scheduler overlaps)
    const bool last_t = (t == kNT);
    float Ec[4][4];
#pragma unroll
    for (int mb = 0; mb < 4; ++mb)
#pragma unroll
      for (int i = 0; i < 4; ++i)
        Ec[mb][i] = __expf(last_t ? (xa[mb][i] + be4[mb][i]) : xa[mb][i]);

    // hardware all-to-all: D[mb] = sum_kb Wt[mb][kb] * P[kb]
    f32x4 D[4];
#pragma unroll
    for (int mb = 0; mb < 4; ++mb) {
      f32x4 d = {0.f, 0.f, 0.f, 0.f};
#pragma unroll
      for (int kb = 0; kb < 4; ++kb)
        d = __builtin_amdgcn_mfma_f32_16x16x16f16(W[mb][kb], P[kb], d, 0, 0, 0);
      D[mb] = d;
    }

    // delay-1 dead-beat scale, E-multiply, convert back to B-fragments
    const float sc = __uint_as_float((unsigned)(127 - eprev) << 23);
    sacc += eprev;

    float m = 0.f, Sv = 0.f;
#pragma unroll
    for (int mb = 0; mb < 4; ++mb) {
      half4_t p;
#pragma unroll
      for (int i = 0; i < 4; ++i) {
        const float pn = D[mb][i] * Ec[mb][i] * sc;
        p[i] = (half1_t)pn;
        m = fmaxf(m, pn);
        Sv += pn;
      }
      P[mb] = p;
    }
    m = chain_max(m);                 // off serial path: gates next scale only
    eprev = ((__float_as_uint(m) >> 23) & 255) - 127;
    Sfin = Sv;

    if (s == nburn - 1) {             // end of burn-in: log2 |alpha| snapshot
      ref = __log2f(chain_sum(Sv)) + (float)sacc;
    }

#pragma unroll
    for (int mb = 0; mb < 4; ++mb) { xa[mb] = xb_[mb]; xb_[mb] = xc[mb]; }
  }

  const float S   = chain_sum(Sfin);
  const float val = (__log2f(S) + (float)sacc) - ref;
  if (q == 0) wsf[ss * kB + bn] = val;   // lanes 0..15 cover the 16 chains
}

// out[b] = ln2 * sum_ss val[ss][b] - pe[b]
__global__ __launch_bounds__(64, 1) void crf_combine(
    const float* __restrict__ wsf, float* __restrict__ out)
{
  const int b = blockIdx.x;
  const int j = threadIdx.x & 63;

  float v = wsf[j * kB + b];   // kS == 64 == wave width
  v = wave_sum(v);

  if (j == 0) out[b] = 0.69314718055994531f * v - wsf[kS * kB + b];
}

}  // namespace

extern "C" void kernel_launch(void* const* d_in, const int* in_sizes, int n_in,
                              void* d_out, int out_size, void* d_ws, size_t ws_size,
                              hipStream_t stream) {
  const float* x  = (const float*)d_in[0];
  const float* U  = (const float*)d_in[1];
  const float* bs = (const float*)d_in[2];
  const float* be = (const float*)d_in[3];
  const int*   y  = (const int*)d_in[4];
  float* out = (float*)d_out;
  float* wsf = (float*)d_ws;

  crf_seg<<<320, 256, 0, stream>>>(x, U, bs, be, y, wsf);
  crf_combine<<<kB, 64, 0, stream>>>(wsf, out);
}